// Round 5
// baseline (1310.644 us; speedup 1.0000x reference)
//
#include <hip/hip_runtime.h>
#include <math.h>

#define NB 16
#define SEQ 1024
#define NT 16384      // NB*SEQ tokens
#define TT 256
#define PP 32
#define NL 8
#define SCALE 0.70710678118654752f
#define LOG2E 1.4426950408889634f
#define CS (SCALE * LOG2E)

typedef float v2f __attribute__((ext_vector_type(2)));

static __device__ __forceinline__ float exp2fast(float x) {
#if __has_builtin(__builtin_amdgcn_exp2f)
  return __builtin_amdgcn_exp2f(x);
#else
  return exp2f(x);
#endif
}

// ---------------- fused preamble: ss + cross-KV(text) + cross-KV(spk) ----------------
__global__ __launch_bounds__(256) void k_pre(const float* __restrict__ tse,
                                             const float* __restrict__ tsw,
                                             const float* __restrict__ tsb,
                                             float* __restrict__ ssa,
                                             const float* __restrict__ text,
                                             const float* __restrict__ spk,
                                             const float* __restrict__ cw,
                                             const float* __restrict__ cb,
                                             float* __restrict__ kvtT,
                                             float* __restrict__ kvsT) {
  __shared__ float sh[64 * 33];
  int tid = threadIdx.x;
  int bx = blockIdx.x;
  if (bx < 32) {
    int idx = bx * 256 + tid;
    int l = idx >> 10;
    int rem = idx & 1023;
    int b = rem >> 6;
    int j = rem & 63;
    const float* wr = tsw + ((size_t)l * 64 + j) * 32;
    const float* xr = tse + b * 32;
    float acc = tsb[l * 64 + j];
#pragma unroll
    for (int e = 0; e < 32; e++) acc = fmaf(xr[e], wr[e], acc);
    ssa[idx] = acc;
    return;
  }
  const float* src;
  float* dst;
  int l, tok0, ntok;
  if (bx < 544) {
    l = (bx - 32) >> 6; tok0 = ((bx - 32) & 63) * 64; ntok = NB * TT; src = text;
    dst = kvtT + (size_t)l * 64 * ntok;
  } else {
    l = (bx - 544) >> 3; tok0 = ((bx - 544) & 7) * 64; ntok = NB * PP; src = spk;
    dst = kvsT + (size_t)l * 64 * ntok;
  }
  const float* w = cw + (size_t)l * 96 * 32 + 32 * 32;  // wk/wv rows
  const float* wb = cb + (size_t)l * 96 + 32;
  for (int i = tid; i < 64 * 32; i += 256) {
    int tl = i >> 5, e = i & 31;
    sh[tl * 33 + e] = src[(size_t)(tok0 + tl) * 32 + e];
  }
  __syncthreads();
  int tl = tid & 63;
  int wv = tid >> 6;
#pragma unroll
  for (int k = 0; k < 16; k++) {
    int j = __builtin_amdgcn_readfirstlane(wv + 4 * k);
    const float* wr = w + j * 32;
    const float* hr = sh + tl * 33;
    float acc = wb[j];
#pragma unroll
    for (int e = 0; e < 32; e++) acc = fmaf(hr[e], wr[e], acc);
    dst[(size_t)j * ntok + tok0 + tl] = acc;
  }
}

// ---------------- register-row helpers ----------------
__device__ __forceinline__ void load_row32(const float* __restrict__ base, int tok, float* r) {
#pragma unroll
  for (int e = 0; e < 32; e++) r[e] = base[(size_t)e * NT + tok];
}

__device__ __forceinline__ void ln_core(float* r) {  // in-place (r - mu)*rstd
  float a0 = 0, a1 = 0, a2 = 0, a3 = 0;
#pragma unroll
  for (int e = 0; e < 32; e += 4) { a0 += r[e]; a1 += r[e + 1]; a2 += r[e + 2]; a3 += r[e + 3]; }
  float mu = ((a0 + a1) + (a2 + a3)) * (1.0f / 32.0f);
  float v0 = 0, v1 = 0, v2 = 0, v3 = 0;
#pragma unroll
  for (int e = 0; e < 32; e += 4) {
    float d0 = r[e] - mu, d1 = r[e + 1] - mu, d2 = r[e + 2] - mu, d3 = r[e + 3] - mu;
    v0 = fmaf(d0, d0, v0); v1 = fmaf(d1, d1, v1); v2 = fmaf(d2, d2, v2); v3 = fmaf(d3, d3, v3);
  }
  float rstd = rsqrtf(((v0 + v1) + (v2 + v3)) * (1.0f / 32.0f) + 1e-6f);
#pragma unroll
  for (int e = 0; e < 32; e++) r[e] = (r[e] - mu) * rstd;
}

// ---------------- A: LN1 + QKV projection (grid (256,4)) ----------------
__global__ __launch_bounds__(256) void k_qkv(const float* __restrict__ hin,
                                             int rowmajor,
                                             float* __restrict__ hA,
                                             const float* __restrict__ mask,
                                             const float* __restrict__ w,   // (96,32)
                                             const float* __restrict__ wb,  // (96)
                                             const float* __restrict__ g,
                                             const float* __restrict__ bv,
                                             float* __restrict__ qkvT) {    // (96, NT)
  int tid = threadIdx.x;
  int tok0 = blockIdx.x * 64;
  int yc = blockIdx.y;  // 0..3
  int tl = tid & 63, wv = tid >> 6;
  int tok = tok0 + tl;
  float r[32];
  if (rowmajor) {
    float m = mask[tok & (SEQ - 1)];
#pragma unroll
    for (int e = 0; e < 32; e++) r[e] = hin[(size_t)tok * 32 + e] * m;
    if (yc == 0 && wv == 0) {
#pragma unroll
      for (int e = 0; e < 32; e++) hA[(size_t)e * NT + tok] = r[e];
    }
  } else {
    load_row32(hin, tok, r);
  }
  ln_core(r);
#pragma unroll
  for (int e = 0; e < 32; e++) r[e] = fmaf(r[e], g[e], bv[e]);
#pragma unroll
  for (int k = 0; k < 6; k++) {
    int j = __builtin_amdgcn_readfirstlane(yc * 24 + wv + 4 * k);
    const float* wr = w + j * 32;
    float acc = wb[j];
#pragma unroll
    for (int e = 0; e < 32; e++) acc = fmaf(r[e], wr[e], acc);
    qkvT[(size_t)j * NT + tok] = acc;
  }
}

// ---------------- attention core (head_dim=2), lane-parallel k ----------------
// wave = 4 row-groups x 16 k-lanes, SETS row-sets => 16*SETS rows/block.
// No max-shift: softmax shift-invariant; scores bounded, exp2 cannot overflow fp32.
template <int SK, int SETS>
__device__ __forceinline__ void attn_core(const float* __restrict__ qb,
                                          const float* __restrict__ kb,
                                          const float* __restrict__ vb,
                                          int kvld,
                                          float* __restrict__ ob) {
  constexpr int RPW = 4 * SETS;        // rows per wave
  constexpr int RPB = 4 * RPW;         // rows per block
  constexpr int NRC = SEQ / RPB;       // row-chunks per (b,h)
  int tid = threadIdx.x;
  int bx = blockIdx.x;
  int rc = bx % NRC, bh = bx / NRC;
  int b = bh >> 4, hh = bh & 15;
  int wv = tid >> 6, lane = tid & 63;
  int rg = lane >> 4, kl = lane & 15;
  int rbase = rc * RPB + wv * RPW + rg;  // + 4*s

  const float* qx = qb + (size_t)(2 * hh) * NT + b * SEQ;
  const float* qy = qx + NT;
  const float* kx = kb + (size_t)(2 * hh) * kvld + b * SK;
  const float* ky = kx + kvld;
  const float* vx = vb + (size_t)(2 * hh) * kvld + b * SK;
  const float* vy = vx + kvld;

  v2f qxx[SETS], qyy[SETS], sum2[SETS], ox2[SETS], oy2[SETS];
#pragma unroll
  for (int s = 0; s < SETS; s++) {
    float q1 = qx[rbase + 4 * s] * CS;
    float q2 = qy[rbase + 4 * s] * CS;
    qxx[s] = (v2f){q1, q1};
    qyy[s] = (v2f){q2, q2};
    sum2[s] = (v2f){0.f, 0.f};
    ox2[s] = (v2f){0.f, 0.f};
    oy2[s] = (v2f){0.f, 0.f};
  }

  if constexpr (SK >= 64) {
#pragma unroll 2
    for (int c = 0; c < SK / 64; c++) {
      int o = c * 64 + kl * 4;
      float4 kx4 = *(const float4*)(kx + o);
      float4 ky4 = *(const float4*)(ky + o);
      float4 vx4 = *(const float4*)(vx + o);
      float4 vy4 = *(const float4*)(vy + o);
      v2f kxlo = (v2f){kx4.x, kx4.y}, kxhi = (v2f){kx4.z, kx4.w};
      v2f kylo = (v2f){ky4.x, ky4.y}, kyhi = (v2f){ky4.z, ky4.w};
      v2f vxlo = (v2f){vx4.x, vx4.y}, vxhi = (v2f){vx4.z, vx4.w};
      v2f vylo = (v2f){vy4.x, vy4.y}, vyhi = (v2f){vy4.z, vy4.w};
#pragma unroll
      for (int s = 0; s < SETS; s++) {
        v2f tlo = __builtin_elementwise_fma(qyy[s], kylo, qxx[s] * kxlo);
        v2f thi = __builtin_elementwise_fma(qyy[s], kyhi, qxx[s] * kxhi);
        v2f elo = (v2f){exp2fast(tlo[0]), exp2fast(tlo[1])};
        v2f ehi = (v2f){exp2fast(thi[0]), exp2fast(thi[1])};
        sum2[s] += elo;
        sum2[s] += ehi;
        ox2[s] = __builtin_elementwise_fma(elo, vxlo, ox2[s]);
        ox2[s] = __builtin_elementwise_fma(ehi, vxhi, ox2[s]);
        oy2[s] = __builtin_elementwise_fma(elo, vylo, oy2[s]);
        oy2[s] = __builtin_elementwise_fma(ehi, vyhi, oy2[s]);
      }
    }
  } else {
    // SK == 32: 16 k-lanes x 2 k
    v2f kx2 = *(const v2f*)(kx + kl * 2);
    v2f ky2 = *(const v2f*)(ky + kl * 2);
    v2f vx2 = *(const v2f*)(vx + kl * 2);
    v2f vy2 = *(const v2f*)(vy + kl * 2);
#pragma unroll
    for (int s = 0; s < SETS; s++) {
      v2f t = __builtin_elementwise_fma(qyy[s], ky2, qxx[s] * kx2);
      v2f e = (v2f){exp2fast(t[0]), exp2fast(t[1])};
      sum2[s] += e;
      ox2[s] = __builtin_elementwise_fma(e, vx2, ox2[s]);
      oy2[s] = __builtin_elementwise_fma(e, vy2, oy2[s]);
    }
  }

  float* oxr = ob + (size_t)(2 * hh) * NT + b * SEQ;
  float* oyr = oxr + NT;
#pragma unroll
  for (int s = 0; s < SETS; s++) {
    float sm = sum2[s][0] + sum2[s][1];
    float ox = ox2[s][0] + ox2[s][1];
    float oy = oy2[s][0] + oy2[s][1];
#pragma unroll
    for (int off = 1; off < 16; off <<= 1) {
      sm += __shfl_xor(sm, off);
      ox += __shfl_xor(ox, off);
      oy += __shfl_xor(oy, off);
    }
    if (kl == 0) {
      float inv = 1.0f / sm;
      int r = rbase + 4 * s;
      oxr[r] = ox * inv;
      oyr[r] = oy * inv;
    }
  }
}

__global__ __launch_bounds__(256) void k_attn_self(const float* __restrict__ qkvT,
                                                   float* __restrict__ oT) {
  attn_core<SEQ, 8>(qkvT, qkvT + (size_t)32 * NT, qkvT + (size_t)64 * NT, NT, oT);
}

__global__ __launch_bounds__(256) void k_attn_cross(const float* __restrict__ q1T,
                                                    const float* __restrict__ q2T,
                                                    const float* __restrict__ kvt,
                                                    const float* __restrict__ kvs,
                                                    float* __restrict__ o1T,
                                                    float* __restrict__ o2T) {
  if (blockIdx.y == 0)
    attn_core<TT, 8>(q1T, kvt, kvt + (size_t)32 * (NB * TT), NB * TT, o1T);
  else
    attn_core<PP, 8>(q2T, kvs, kvs + (size_t)32 * (NB * PP), NB * PP, o2T);
}

// ---------------- C: self out-proj + residual + LN2/LN22 + both cross-Q (grid (64,2)) ----------------
__global__ __launch_bounds__(256) void k_projq(const float* __restrict__ o1T,
                                               const float* __restrict__ aow,  // (32,32)
                                               const float* __restrict__ aob,
                                               const float* __restrict__ hA,   // read
                                               float* __restrict__ hB,         // write (yc0)
                                               const float* __restrict__ cwq,  // (32,32) wq rows
                                               const float* __restrict__ cbq,
                                               const float* __restrict__ g2, const float* __restrict__ b2,
                                               const float* __restrict__ g22, const float* __restrict__ b22,
                                               float* __restrict__ q1T, float* __restrict__ q2T) {
  int tid = threadIdx.x;
  int tok = blockIdx.x * 256 + tid;
  int yc = blockIdx.y;  // 0: q1 (+hB write), 1: q2
  float o[32], h[32];
  load_row32(o1T, tok, o);
#pragma unroll
  for (int e = 0; e < 32; e++) {
    const float* wr = aow + e * 32;
    float acc = aob[e];
#pragma unroll
    for (int i = 0; i < 32; i++) acc = fmaf(o[i], wr[i], acc);
    h[e] = hA[(size_t)e * NT + tok] + acc;
  }
  if (yc == 0) {
#pragma unroll
    for (int e = 0; e < 32; e++) hB[(size_t)e * NT + tok] = h[e];
  }
  ln_core(h);
  const float* g = yc ? g22 : g2;
  const float* bb = yc ? b22 : b2;
  float* dst = yc ? q2T : q1T;
#pragma unroll
  for (int e = 0; e < 32; e++) h[e] = fmaf(h[e], g[e], bb[e]);
#pragma unroll
  for (int j = 0; j < 32; j++) {
    const float* wr = cwq + j * 32;
    float acc = cbq[j];
#pragma unroll
    for (int i = 0; i < 32; i++) acc = fmaf(h[i], wr[i], acc);
    dst[(size_t)j * NT + tok] = acc;
  }
}

// ---------------- E: cross out-proj + residual + LN3/AdaLN + fc1 + gelu (grid (64,4)) ----------------
__global__ __launch_bounds__(256) void k_proj_fc1(const float* __restrict__ o1T,
                                                  const float* __restrict__ o2T,
                                                  const float* __restrict__ cow,
                                                  const float* __restrict__ cob,
                                                  const float* __restrict__ hB,  // read
                                                  float* __restrict__ hC,        // write (yc0) — slab shared with hA (dead)
                                                  const float* __restrict__ ssl, // (NB,64)
                                                  const float* __restrict__ g, const float* __restrict__ bv,
                                                  const float* __restrict__ w1, const float* __restrict__ b1,
                                                  float* __restrict__ uT) {      // (128,NT)
  int tid = threadIdx.x;
  int tok = blockIdx.x * 256 + tid;
  int yc = blockIdx.y;  // 0..3
  int b = tok >> 10;
  float o[32], h[32];
#pragma unroll
  for (int e = 0; e < 32; e++)
    o[e] = o1T[(size_t)e * NT + tok] + o2T[(size_t)e * NT + tok];
#pragma unroll
  for (int e = 0; e < 32; e++) {
    const float* wr = cow + e * 32;
    float acc = 2.0f * cob[e];
#pragma unroll
    for (int i = 0; i < 32; i++) acc = fmaf(o[i], wr[i], acc);
    h[e] = hB[(size_t)e * NT + tok] + acc;
  }
  if (yc == 0) {
#pragma unroll
    for (int e = 0; e < 32; e++) hC[(size_t)e * NT + tok] = h[e];
  }
  ln_core(h);
  const float* sc = ssl + b * 64;
#pragma unroll
  for (int e = 0; e < 32; e++) {
    float ln = fmaf(h[e], g[e], bv[e]);
    h[e] = fmaf(ln, 1.0f + sc[e], sc[32 + e]);
  }
#pragma unroll
  for (int k = 0; k < 32; k++) {
    int j = yc * 32 + k;
    const float* wr = w1 + j * 32;
    float acc = b1[j];
#pragma unroll
    for (int i = 0; i < 32; i++) acc = fmaf(h[i], wr[i], acc);
    float ge = 0.5f * acc * (1.0f + erff(acc * 0.70710678118654752f));
    uT[(size_t)j * NT + tok] = ge;
  }
}

// ---------------- F: fc2 + residual + mask (grid (256,2)); hio updated IN PLACE ----------------
__global__ __launch_bounds__(256) void k_fc2(const float* __restrict__ uT,
                                             float* hio,                     // h in (residual) / h out, same slab
                                             float* __restrict__ out_rm,     // d_out (last) or null
                                             const float* __restrict__ mask,
                                             const float* __restrict__ w2,   // (32,128)
                                             const float* __restrict__ b2) {
  __shared__ __align__(16) float shu[64 * 132];
  int tid = threadIdx.x;
  int tok0 = blockIdx.x * 64, yc = blockIdx.y;  // 0..1
  for (int i = tid; i < 64 * 128; i += 256) {
    int e = i >> 6, tl = i & 63;
    shu[tl * 132 + e] = uT[(size_t)e * NT + tok0 + tl];
  }
  __syncthreads();
  int tl = tid & 63, wv = tid >> 6;
  int tok = tok0 + tl;
  int j0 = __builtin_amdgcn_readfirstlane(yc * 16 + wv);
  int j1 = __builtin_amdgcn_readfirstlane(j0 + 4);
  int j2 = __builtin_amdgcn_readfirstlane(j0 + 8);
  int j3 = __builtin_amdgcn_readfirstlane(j0 + 12);
  const float* w0 = w2 + j0 * 128;
  const float* w1 = w2 + j1 * 128;
  const float* w2r = w2 + j2 * 128;
  const float* w3 = w2 + j3 * 128;
  float a0 = b2[j0], a1 = b2[j1], a2 = b2[j2], a3 = b2[j3];
  const float4* ur = (const float4*)(shu + tl * 132);
#pragma unroll
  for (int m = 0; m < 32; m++) {
    float4 t = ur[m];
    a0 = fmaf(t.x, w0[4 * m], a0); a0 = fmaf(t.y, w0[4 * m + 1], a0);
    a0 = fmaf(t.z, w0[4 * m + 2], a0); a0 = fmaf(t.w, w0[4 * m + 3], a0);
    a1 = fmaf(t.x, w1[4 * m], a1); a1 = fmaf(t.y, w1[4 * m + 1], a1);
    a1 = fmaf(t.z, w1[4 * m + 2], a1); a1 = fmaf(t.w, w1[4 * m + 3], a1);
    a2 = fmaf(t.x, w2r[4 * m], a2); a2 = fmaf(t.y, w2r[4 * m + 1], a2);
    a2 = fmaf(t.z, w2r[4 * m + 2], a2); a2 = fmaf(t.w, w2r[4 * m + 3], a2);
    a3 = fmaf(t.x, w3[4 * m], a3); a3 = fmaf(t.y, w3[4 * m + 1], a3);
    a3 = fmaf(t.z, w3[4 * m + 2], a3); a3 = fmaf(t.w, w3[4 * m + 3], a3);
  }
  float mk = mask[tok & (SEQ - 1)];
  size_t g0 = (size_t)j0 * NT + tok, g1 = (size_t)j1 * NT + tok;
  size_t g2i = (size_t)j2 * NT + tok, g3 = (size_t)j3 * NT + tok;
  float r0 = (hio[g0] + a0) * mk;
  float r1 = (hio[g1] + a1) * mk;
  float r2 = (hio[g2i] + a2) * mk;
  float r3 = (hio[g3] + a3) * mk;
  if (out_rm) {
    out_rm[(size_t)tok * 32 + j0] = r0;
    out_rm[(size_t)tok * 32 + j1] = r1;
    out_rm[(size_t)tok * 32 + j2] = r2;
    out_rm[(size_t)tok * 32 + j3] = r3;
  } else {
    hio[g0] = r0;
    hio[g1] = r1;
    hio[g2i] = r2;
    hio[g3] = r3;
  }
}

extern "C" void kernel_launch(void* const* d_in, const int* in_sizes, int n_in,
                              void* d_out, int out_size, void* d_ws, size_t ws_size,
                              hipStream_t stream) {
  const float* x = (const float*)d_in[0];
  const float* spk = (const float*)d_in[1];
  const float* text = (const float*)d_in[2];
  const float* tse = (const float*)d_in[3];
  const float* mask = (const float*)d_in[4];
  const float* ln1_g = (const float*)d_in[5];
  const float* ln1_b = (const float*)d_in[6];
  const float* ln2_g = (const float*)d_in[7];
  const float* ln2_b = (const float*)d_in[8];
  const float* ln22_g = (const float*)d_in[9];
  const float* ln22_b = (const float*)d_in[10];
  const float* ln3_g = (const float*)d_in[11];
  const float* ln3_b = (const float*)d_in[12];
  const float* aw = (const float*)d_in[13];
  const float* ab = (const float*)d_in[14];
  const float* aow = (const float*)d_in[15];
  const float* aob = (const float*)d_in[16];
  const float* cw = (const float*)d_in[17];
  const float* cb = (const float*)d_in[18];
  const float* cow = (const float*)d_in[19];
  const float* cob = (const float*)d_in[20];
  const float* tsw = (const float*)d_in[21];
  const float* tsb = (const float*)d_in[22];
  const float* f1w = (const float*)d_in[23];
  const float* f1b = (const float*)d_in[24];
  const float* f2w = (const float*)d_in[25];
  const float* f2b = (const float*)d_in[26];

  // 8 slabs of 32*NT floats (liveness-colored; total = R3's proven 26.25MB):
  //   slabs 0-2: qkvT [A→B];  slab 0: q1T, slab 1: q2T [C→D];  slabs 0-3: uT [E→F]
  //   slab 4: hA [Fprev→C] == hC [E→F] (k_fc2 updates in place)
  //   slab 5: o1T (self [B→C], cross1 [D→E]);  slab 6: o2T [D→E];  slab 7: hB [C→E]
  float* ws = (float*)d_ws;
  const size_t SL = (size_t)32 * NT;
  float* uT = ws;          // slabs 0-3
  float* qkvT = ws;        // slabs 0-2
  float* q1T = ws;         // slab 0
  float* q2T = ws + SL;    // slab 1
  float* hA = ws + 4 * SL; // slab 4 (also hC)
  float* o1T = ws + 5 * SL;
  float* o2T = ws + 6 * SL;
  float* hB = ws + 7 * SL;
  float* kvtT = ws + 8 * SL;                         // NL*64*(NB*TT)
  float* kvsT = kvtT + (size_t)NL * 64 * (NB * TT);  // NL*64*(NB*PP)
  float* ssa = kvsT + (size_t)NL * 64 * (NB * PP);   // NL*NB*64

  k_pre<<<608, 256, 0, stream>>>(tse, tsw, tsb, ssa, text, spk, cw, cb, kvtT, kvsT);

  for (int l = 0; l < NL; l++) {
    k_qkv<<<dim3(256, 4), 256, 0, stream>>>((l == 0) ? x : hA, (l == 0) ? 1 : 0, hA, mask,
                                            aw + (size_t)l * 96 * 32, ab + l * 96,
                                            ln1_g + l * 32, ln1_b + l * 32, qkvT);
    k_attn_self<<<2048, 256, 0, stream>>>(qkvT, o1T);
    k_projq<<<dim3(64, 2), 256, 0, stream>>>(o1T, aow + (size_t)l * 32 * 32, aob + l * 32,
                                             hA, hB,
                                             cw + (size_t)l * 96 * 32, cb + l * 96,
                                             ln2_g + l * 32, ln2_b + l * 32,
                                             ln22_g + l * 32, ln22_b + l * 32, q1T, q2T);
    k_attn_cross<<<dim3(2048, 2), 256, 0, stream>>>(q1T, q2T,
                                                    kvtT + (size_t)l * 64 * (NB * TT),
                                                    kvsT + (size_t)l * 64 * (NB * PP),
                                                    o1T, o2T);
    k_proj_fc1<<<dim3(64, 4), 256, 0, stream>>>(o1T, o2T,
                                                cow + (size_t)l * 32 * 32, cob + l * 32,
                                                hB, hA, ssa + (size_t)l * NB * 64,
                                                ln3_g + l * 32, ln3_b + l * 32,
                                                f1w + (size_t)l * 128 * 32, f1b + l * 128, uT);
    k_fc2<<<dim3(256, 2), 256, 0, stream>>>(uT, hA, (l == NL - 1) ? (float*)d_out : nullptr,
                                            mask, f2w + (size_t)l * 32 * 128, f2b + l * 32);
  }
}

// Round 8
// 971.262 us; speedup vs baseline: 1.3494x; 1.3494x over previous
//
#include <hip/hip_runtime.h>
#include <math.h>

#define NB 16
#define SEQ 1024
#define NT 16384      // NB*SEQ tokens
#define TT 256
#define PP 32
#define NL 8
#define SCALE 0.70710678118654752f
#define LOG2E 1.4426950408889634f
#define CS (SCALE * LOG2E)

static __device__ __forceinline__ float exp2fast(float x) {
#if __has_builtin(__builtin_amdgcn_exp2f)
  return __builtin_amdgcn_exp2f(x);
#else
  return exp2f(x);
#endif
}

// ---------------- fused preamble: ss + cross-KV(text) + cross-KV(spk) ----------------
__global__ __launch_bounds__(256) void k_pre(const float* __restrict__ tse,
                                             const float* __restrict__ tsw,
                                             const float* __restrict__ tsb,
                                             float* __restrict__ ssa,
                                             const float* __restrict__ text,
                                             const float* __restrict__ spk,
                                             const float* __restrict__ cw,
                                             const float* __restrict__ cb,
                                             float* __restrict__ kvtT,
                                             float* __restrict__ kvsT) {
  __shared__ float sh[64 * 33];
  int tid = threadIdx.x;
  int bx = blockIdx.x;
  if (bx < 32) {
    int idx = bx * 256 + tid;
    int l = idx >> 10;
    int rem = idx & 1023;
    int b = rem >> 6;
    int j = rem & 63;
    const float* wr = tsw + ((size_t)l * 64 + j) * 32;
    const float* xr = tse + b * 32;
    float acc = tsb[l * 64 + j];
#pragma unroll
    for (int e = 0; e < 32; e++) acc = fmaf(xr[e], wr[e], acc);
    ssa[idx] = acc;
    return;
  }
  const float* src;
  float* dst;
  int l, tok0, ntok;
  if (bx < 544) {
    l = (bx - 32) >> 6; tok0 = ((bx - 32) & 63) * 64; ntok = NB * TT; src = text;
    dst = kvtT + (size_t)l * 64 * ntok;
  } else {
    l = (bx - 544) >> 3; tok0 = ((bx - 544) & 7) * 64; ntok = NB * PP; src = spk;
    dst = kvsT + (size_t)l * 64 * ntok;
  }
  const float* w = cw + (size_t)l * 96 * 32 + 32 * 32;  // wk/wv rows
  const float* wb = cb + (size_t)l * 96 + 32;
  for (int i = tid; i < 64 * 32; i += 256) {
    int tl = i >> 5, e = i & 31;
    sh[tl * 33 + e] = src[(size_t)(tok0 + tl) * 32 + e];
  }
  __syncthreads();
  int tl = tid & 63;
  int wv = tid >> 6;
#pragma unroll
  for (int k = 0; k < 16; k++) {
    int j = __builtin_amdgcn_readfirstlane(wv + 4 * k);
    const float* wr = w + j * 32;
    const float* hr = sh + tl * 33;
    float acc = wb[j];
#pragma unroll
    for (int e = 0; e < 32; e++) acc = fmaf(hr[e], wr[e], acc);
    dst[(size_t)j * ntok + tok0 + tl] = acc;
  }
}

// ---------------- register-row helpers ----------------
__device__ __forceinline__ void load_row32(const float* __restrict__ base, int tok, float* r) {
#pragma unroll
  for (int e = 0; e < 32; e++) r[e] = base[(size_t)e * NT + tok];
}

__device__ __forceinline__ void ln_core(float* r) {  // in-place (r - mu)*rstd
  float a0 = 0, a1 = 0, a2 = 0, a3 = 0;
#pragma unroll
  for (int e = 0; e < 32; e += 4) { a0 += r[e]; a1 += r[e + 1]; a2 += r[e + 2]; a3 += r[e + 3]; }
  float mu = ((a0 + a1) + (a2 + a3)) * (1.0f / 32.0f);
  float v0 = 0, v1 = 0, v2 = 0, v3 = 0;
#pragma unroll
  for (int e = 0; e < 32; e += 4) {
    float d0 = r[e] - mu, d1 = r[e + 1] - mu, d2 = r[e + 2] - mu, d3 = r[e + 3] - mu;
    v0 = fmaf(d0, d0, v0); v1 = fmaf(d1, d1, v1); v2 = fmaf(d2, d2, v2); v3 = fmaf(d3, d3, v3);
  }
  float rstd = rsqrtf(((v0 + v1) + (v2 + v3)) * (1.0f / 32.0f) + 1e-6f);
#pragma unroll
  for (int e = 0; e < 32; e++) r[e] = (r[e] - mu) * rstd;
}

// ---------------- LN1 + QKV projection (grid (256,4)) ----------------
__global__ __launch_bounds__(256) void k_qkv(const float* __restrict__ hin,
                                             int rowmajor,
                                             float* __restrict__ hT,
                                             const float* __restrict__ mask,
                                             const float* __restrict__ w,   // (96,32)
                                             const float* __restrict__ wb,  // (96)
                                             const float* __restrict__ g,
                                             const float* __restrict__ bv,
                                             float* __restrict__ qkvT) {    // (96, NT)
  int tid = threadIdx.x;
  int tok0 = blockIdx.x * 64;
  int yc = blockIdx.y;  // 0..3
  int tl = tid & 63, wv = tid >> 6;
  int tok = tok0 + tl;
  float r[32];
  if (rowmajor) {
    float m = mask[tok & (SEQ - 1)];
#pragma unroll
    for (int e = 0; e < 32; e++) r[e] = hin[(size_t)tok * 32 + e] * m;
    if (yc == 0 && wv == 0) {
#pragma unroll
      for (int e = 0; e < 32; e++) hT[(size_t)e * NT + tok] = r[e];
    }
  } else {
    load_row32(hin, tok, r);
  }
  ln_core(r);
#pragma unroll
  for (int e = 0; e < 32; e++) r[e] = fmaf(r[e], g[e], bv[e]);
#pragma unroll
  for (int k = 0; k < 6; k++) {
    int j = __builtin_amdgcn_readfirstlane(yc * 24 + wv + 4 * k);
    const float* wr = w + j * 32;
    float acc = wb[j];
#pragma unroll
    for (int e = 0; e < 32; e++) acc = fmaf(r[e], wr[e], acc);
    qkvT[(size_t)j * NT + tok] = acc;
  }
}

// ---------------- LN2/LN22 + cross-Q projections (grid (256,4)) ----------------
__global__ __launch_bounds__(256) void k_q12(const float* __restrict__ hT,
                                             const float* __restrict__ w,   // wq rows (32,32)
                                             const float* __restrict__ wb,
                                             const float* __restrict__ g2, const float* __restrict__ b2,
                                             const float* __restrict__ g22, const float* __restrict__ b22,
                                             float* __restrict__ q1T, float* __restrict__ q2T) {
  int tid = threadIdx.x;
  int tok0 = blockIdx.x * 64, yc = blockIdx.y;  // 0..3
  int tl = tid & 63, wv = tid >> 6;
  int tok = tok0 + tl;
  float r[32];
  load_row32(hT, tok, r);
  ln_core(r);
  const float* g = (yc >= 2) ? g22 : g2;
  const float* bb = (yc >= 2) ? b22 : b2;
  float* dst = (yc >= 2) ? q2T : q1T;
#pragma unroll
  for (int e = 0; e < 32; e++) r[e] = fmaf(r[e], g[e], bb[e]);
  int jbase = (yc & 1) * 16;
#pragma unroll
  for (int k = 0; k < 4; k++) {
    int j = __builtin_amdgcn_readfirstlane(jbase + wv + 4 * k);
    const float* wr = w + j * 32;
    float acc = wb[j];
#pragma unroll
    for (int e = 0; e < 32; e++) acc = fmaf(r[e], wr[e], acc);
    dst[(size_t)j * NT + tok] = acc;
  }
}

// ---------------- out-projection + residual (grid (256,4)) ----------------
__global__ __launch_bounds__(256) void k_proj_add(const float* __restrict__ s1T,
                                                  const float* __restrict__ s2T,  // may be null
                                                  const float* __restrict__ w,    // (32,32)
                                                  const float* __restrict__ wb, float bmult,
                                                  float* __restrict__ hT) {
  int tid = threadIdx.x;
  int tok0 = blockIdx.x * 64, yc = blockIdx.y;  // 0..3
  int tl = tid & 63, wv = tid >> 6;
  int tok = tok0 + tl;
  float r[32];
  if (s2T) {
#pragma unroll
    for (int e = 0; e < 32; e++)
      r[e] = s1T[(size_t)e * NT + tok] + s2T[(size_t)e * NT + tok];
  } else {
    load_row32(s1T, tok, r);
  }
#pragma unroll
  for (int k = 0; k < 2; k++) {
    int j = __builtin_amdgcn_readfirstlane(yc * 8 + wv + 4 * k);
    const float* wr = w + j * 32;
    float acc = bmult * wb[j];
#pragma unroll
    for (int e = 0; e < 32; e++) acc = fmaf(r[e], wr[e], acc);
    size_t gi = (size_t)j * NT + tok;
    hT[gi] += acc;
  }
}

// ---------------- attention core (head_dim=2), lane-parallel k, pure scalar ----------------
// wave = 4 row-groups x 16 k-lanes, SETS row-sets => 16*SETS rows/block.
// No max-shift: softmax shift-invariant; scores bounded, exp2 cannot overflow fp32.
// Scalar math on float4 components directly — no v2f packaging movs, no pk asm.
template <int SK, int SETS>
__device__ __forceinline__ void attn_core(const float* __restrict__ qb,
                                          const float* __restrict__ kb,
                                          const float* __restrict__ vb,
                                          int kvld,
                                          float* __restrict__ ob) {
  constexpr int RPW = 4 * SETS;        // rows per wave
  constexpr int RPB = 4 * RPW;         // rows per block
  constexpr int NRC = SEQ / RPB;       // row-chunks per (b,h)
  int tid = threadIdx.x;
  int bx = blockIdx.x;
  int rc = bx % NRC, bh = bx / NRC;
  int b = bh >> 4, hh = bh & 15;
  int wv = tid >> 6, lane = tid & 63;
  int rg = lane >> 4, kl = lane & 15;
  int rbase = rc * RPB + wv * RPW + rg;  // + 4*s

  const float* qxp = qb + (size_t)(2 * hh) * NT + b * SEQ;
  const float* qyp = qxp + NT;
  const float* kx = kb + (size_t)(2 * hh) * kvld + b * SK;
  const float* ky = kx + kvld;
  const float* vx = vb + (size_t)(2 * hh) * kvld + b * SK;
  const float* vy = vx + kvld;

  float qx[SETS], qy[SETS], sum[SETS], ox[SETS], oy[SETS];
#pragma unroll
  for (int s = 0; s < SETS; s++) {
    qx[s] = qxp[rbase + 4 * s] * CS;
    qy[s] = qyp[rbase + 4 * s] * CS;
    sum[s] = 0.f; ox[s] = 0.f; oy[s] = 0.f;
  }

  if constexpr (SK >= 64) {
#pragma unroll 2
    for (int c = 0; c < SK / 64; c++) {
      int o = c * 64 + kl * 4;
      float4 k4x = *(const float4*)(kx + o);
      float4 k4y = *(const float4*)(ky + o);
      float4 v4x = *(const float4*)(vx + o);
      float4 v4y = *(const float4*)(vy + o);
#pragma unroll
      for (int s = 0; s < SETS; s++) {
        float e0 = exp2fast(fmaf(qy[s], k4y.x, qx[s] * k4x.x));
        float e1 = exp2fast(fmaf(qy[s], k4y.y, qx[s] * k4x.y));
        float e2 = exp2fast(fmaf(qy[s], k4y.z, qx[s] * k4x.z));
        float e3 = exp2fast(fmaf(qy[s], k4y.w, qx[s] * k4x.w));
        sum[s] += (e0 + e1) + (e2 + e3);
        ox[s] = fmaf(e0, v4x.x, ox[s]);
        ox[s] = fmaf(e1, v4x.y, ox[s]);
        ox[s] = fmaf(e2, v4x.z, ox[s]);
        ox[s] = fmaf(e3, v4x.w, ox[s]);
        oy[s] = fmaf(e0, v4y.x, oy[s]);
        oy[s] = fmaf(e1, v4y.y, oy[s]);
        oy[s] = fmaf(e2, v4y.z, oy[s]);
        oy[s] = fmaf(e3, v4y.w, oy[s]);
      }
    }
  } else {
    // SK == 32: 16 k-lanes x 2 k
    float2 k2x = *(const float2*)(kx + kl * 2);
    float2 k2y = *(const float2*)(ky + kl * 2);
    float2 v2x = *(const float2*)(vx + kl * 2);
    float2 v2y = *(const float2*)(vy + kl * 2);
#pragma unroll
    for (int s = 0; s < SETS; s++) {
      float e0 = exp2fast(fmaf(qy[s], k2y.x, qx[s] * k2x.x));
      float e1 = exp2fast(fmaf(qy[s], k2y.y, qx[s] * k2x.y));
      sum[s] += e0 + e1;
      ox[s] = fmaf(e0, v2x.x, ox[s]);
      ox[s] = fmaf(e1, v2x.y, ox[s]);
      oy[s] = fmaf(e0, v2y.x, oy[s]);
      oy[s] = fmaf(e1, v2y.y, oy[s]);
    }
  }

  float* oxr = ob + (size_t)(2 * hh) * NT + b * SEQ;
  float* oyr = oxr + NT;
#pragma unroll
  for (int s = 0; s < SETS; s++) {
    float sm = sum[s];
    float o1 = ox[s];
    float o2 = oy[s];
#pragma unroll
    for (int off = 1; off < 16; off <<= 1) {
      sm += __shfl_xor(sm, off);
      o1 += __shfl_xor(o1, off);
      o2 += __shfl_xor(o2, off);
    }
    if (kl == 0) {
      float inv = 1.0f / sm;
      int r = rbase + 4 * s;
      oxr[r] = o1 * inv;
      oyr[r] = o2 * inv;
    }
  }
}

__global__ __launch_bounds__(256) void k_attn_self(const float* __restrict__ qkvT,
                                                   float* __restrict__ oT) {
  attn_core<SEQ, 8>(qkvT, qkvT + (size_t)32 * NT, qkvT + (size_t)64 * NT, NT, oT);
}

__global__ __launch_bounds__(256) void k_attn_cross(const float* __restrict__ q1T,
                                                    const float* __restrict__ q2T,
                                                    const float* __restrict__ kvt,
                                                    const float* __restrict__ kvs,
                                                    float* __restrict__ o1T,
                                                    float* __restrict__ o2T) {
  if (blockIdx.y == 0)
    attn_core<TT, 8>(q1T, kvt, kvt + (size_t)32 * (NB * TT), NB * TT, o1T);
  else
    attn_core<PP, 8>(q2T, kvs, kvs + (size_t)32 * (NB * PP), NB * PP, o2T);
}

// ---------------- LN3 + AdaLN + fc1 + gelu (grid (256,4)) ----------------
__global__ __launch_bounds__(256) void k_fc1(const float* __restrict__ hT,
                                             const float* __restrict__ ssl,  // (NB,64)
                                             const float* __restrict__ g, const float* __restrict__ bv,
                                             const float* __restrict__ w1, const float* __restrict__ b1,
                                             float* __restrict__ uT) {  // (128, NT)
  int tid = threadIdx.x;
  int tok0 = blockIdx.x * 64, yc = blockIdx.y;  // 0..3
  int tl = tid & 63, wv = tid >> 6;
  int tok = tok0 + tl;
  int b = tok0 >> 10;
  const float* sc = ssl + b * 64;
  float r[32];
  load_row32(hT, tok, r);
  ln_core(r);
#pragma unroll
  for (int e = 0; e < 32; e++) {
    float ln = fmaf(r[e], g[e], bv[e]);
    r[e] = fmaf(ln, 1.0f + sc[e], sc[32 + e]);
  }
#pragma unroll
  for (int k = 0; k < 8; k++) {
    int j = __builtin_amdgcn_readfirstlane(yc * 32 + wv + 4 * k);
    const float* wr = w1 + j * 32;
    float acc = b1[j];
#pragma unroll
    for (int e = 0; e < 32; e++) acc = fmaf(r[e], wr[e], acc);
    float ge = 0.5f * acc * (1.0f + erff(acc * 0.70710678118654752f));
    uT[(size_t)j * NT + tok] = ge;
  }
}

// ---------------- fc2 + residual + mask (grid (256,2)); hT updated IN PLACE ----------------
__global__ __launch_bounds__(256) void k_fc2(const float* __restrict__ uT,
                                             float* hT,                      // h in (residual) / h out
                                             float* __restrict__ out_rm,     // d_out (last) or null
                                             const float* __restrict__ mask,
                                             const float* __restrict__ w2,   // (32,128)
                                             const float* __restrict__ b2) {
  __shared__ __align__(16) float shu[64 * 132];
  int tid = threadIdx.x;
  int tok0 = blockIdx.x * 64, yc = blockIdx.y;  // 0..1
  for (int i = tid; i < 64 * 128; i += 256) {
    int e = i >> 6, tl = i & 63;
    shu[tl * 132 + e] = uT[(size_t)e * NT + tok0 + tl];
  }
  __syncthreads();
  int tl = tid & 63, wv = tid >> 6;
  int tok = tok0 + tl;
  int j0 = __builtin_amdgcn_readfirstlane(yc * 16 + wv);
  int j1 = __builtin_amdgcn_readfirstlane(j0 + 4);
  int j2 = __builtin_amdgcn_readfirstlane(j0 + 8);
  int j3 = __builtin_amdgcn_readfirstlane(j0 + 12);
  const float* w0 = w2 + j0 * 128;
  const float* w1 = w2 + j1 * 128;
  const float* w2r = w2 + j2 * 128;
  const float* w3 = w2 + j3 * 128;
  float a0 = b2[j0], a1 = b2[j1], a2 = b2[j2], a3 = b2[j3];
  const float4* ur = (const float4*)(shu + tl * 132);
#pragma unroll
  for (int m = 0; m < 32; m++) {
    float4 t = ur[m];
    a0 = fmaf(t.x, w0[4 * m], a0); a0 = fmaf(t.y, w0[4 * m + 1], a0);
    a0 = fmaf(t.z, w0[4 * m + 2], a0); a0 = fmaf(t.w, w0[4 * m + 3], a0);
    a1 = fmaf(t.x, w1[4 * m], a1); a1 = fmaf(t.y, w1[4 * m + 1], a1);
    a1 = fmaf(t.z, w1[4 * m + 2], a1); a1 = fmaf(t.w, w1[4 * m + 3], a1);
    a2 = fmaf(t.x, w2r[4 * m], a2); a2 = fmaf(t.y, w2r[4 * m + 1], a2);
    a2 = fmaf(t.z, w2r[4 * m + 2], a2); a2 = fmaf(t.w, w2r[4 * m + 3], a2);
    a3 = fmaf(t.x, w3[4 * m], a3); a3 = fmaf(t.y, w3[4 * m + 1], a3);
    a3 = fmaf(t.z, w3[4 * m + 2], a3); a3 = fmaf(t.w, w3[4 * m + 3], a3);
  }
  float mk = mask[tok & (SEQ - 1)];
  size_t g0 = (size_t)j0 * NT + tok, g1 = (size_t)j1 * NT + tok;
  size_t g2i = (size_t)j2 * NT + tok, g3 = (size_t)j3 * NT + tok;
  float r0 = (hT[g0] + a0) * mk;
  float r1 = (hT[g1] + a1) * mk;
  float r2 = (hT[g2i] + a2) * mk;
  float r3 = (hT[g3] + a3) * mk;
  if (out_rm) {
    out_rm[(size_t)tok * 32 + j0] = r0;
    out_rm[(size_t)tok * 32 + j1] = r1;
    out_rm[(size_t)tok * 32 + j2] = r2;
    out_rm[(size_t)tok * 32 + j3] = r3;
  } else {
    hT[g0] = r0;
    hT[g1] = r1;
    hT[g2i] = r2;
    hT[g3] = r3;
  }
}

extern "C" void kernel_launch(void* const* d_in, const int* in_sizes, int n_in,
                              void* d_out, int out_size, void* d_ws, size_t ws_size,
                              hipStream_t stream) {
  const float* x = (const float*)d_in[0];
  const float* spk = (const float*)d_in[1];
  const float* text = (const float*)d_in[2];
  const float* tse = (const float*)d_in[3];
  const float* mask = (const float*)d_in[4];
  const float* ln1_g = (const float*)d_in[5];
  const float* ln1_b = (const float*)d_in[6];
  const float* ln2_g = (const float*)d_in[7];
  const float* ln2_b = (const float*)d_in[8];
  const float* ln22_g = (const float*)d_in[9];
  const float* ln22_b = (const float*)d_in[10];
  const float* ln3_g = (const float*)d_in[11];
  const float* ln3_b = (const float*)d_in[12];
  const float* aw = (const float*)d_in[13];
  const float* ab = (const float*)d_in[14];
  const float* aow = (const float*)d_in[15];
  const float* aob = (const float*)d_in[16];
  const float* cw = (const float*)d_in[17];
  const float* cb = (const float*)d_in[18];
  const float* cow = (const float*)d_in[19];
  const float* cob = (const float*)d_in[20];
  const float* tsw = (const float*)d_in[21];
  const float* tsb = (const float*)d_in[22];
  const float* f1w = (const float*)d_in[23];
  const float* f1b = (const float*)d_in[24];
  const float* f2w = (const float*)d_in[25];
  const float* f2b = (const float*)d_in[26];

  // R3-proven workspace layout (26.25 MB total)
  float* ws = (float*)d_ws;
  float* hT = ws;                                    // 32*NT
  float* qkvT = hT + (size_t)32 * NT;                // 96*NT
  float* o1T = qkvT + (size_t)96 * NT;               // 32*NT
  float* o2T = o1T + (size_t)32 * NT;                // 32*NT
  float* q1T = o2T + (size_t)32 * NT;                // 32*NT
  float* q2T = q1T + (size_t)32 * NT;                // 32*NT
  float* kvtT = q2T + (size_t)32 * NT;               // NL*64*(NB*TT)
  float* kvsT = kvtT + (size_t)NL * 64 * (NB * TT);  // NL*64*(NB*PP)
  float* ssa = kvsT + (size_t)NL * 64 * (NB * PP);   // NL*NB*64
  float* uT = o1T;  // (128,NT) aliases o1T..q2T (dead when fc1/fc2 run)

  k_pre<<<608, 256, 0, stream>>>(tse, tsw, tsb, ssa, text, spk, cw, cb, kvtT, kvsT);

  for (int l = 0; l < NL; l++) {
    k_qkv<<<dim3(256, 4), 256, 0, stream>>>((l == 0) ? x : hT, (l == 0) ? 1 : 0, hT, mask,
                                            aw + (size_t)l * 96 * 32, ab + l * 96,
                                            ln1_g + l * 32, ln1_b + l * 32, qkvT);
    k_attn_self<<<2048, 256, 0, stream>>>(qkvT, o1T);
    k_proj_add<<<dim3(256, 4), 256, 0, stream>>>(o1T, nullptr,
                                                 aow + (size_t)l * 32 * 32, aob + l * 32, 1.0f, hT);
    k_q12<<<dim3(256, 4), 256, 0, stream>>>(hT, cw + (size_t)l * 96 * 32, cb + l * 96,
                                            ln2_g + l * 32, ln2_b + l * 32,
                                            ln22_g + l * 32, ln22_b + l * 32, q1T, q2T);
    k_attn_cross<<<dim3(2048, 2), 256, 0, stream>>>(q1T, q2T,
                                                    kvtT + (size_t)l * 64 * (NB * TT),
                                                    kvsT + (size_t)l * 64 * (NB * PP),
                                                    o1T, o2T);
    k_proj_add<<<dim3(256, 4), 256, 0, stream>>>(o1T, o2T,
                                                 cow + (size_t)l * 32 * 32, cob + l * 32, 2.0f, hT);
    k_fc1<<<dim3(256, 4), 256, 0, stream>>>(hT, ssa + (size_t)l * NB * 64,
                                            ln3_g + l * 32, ln3_b + l * 32,
                                            f1w + (size_t)l * 128 * 32, f1b + l * 128, uT);
    k_fc2<<<dim3(256, 2), 256, 0, stream>>>(uT, hT, (l == NL - 1) ? (float*)d_out : nullptr,
                                            mask, f2w + (size_t)l * 32 * 128, f2b + l * 32);
  }
}